// Round 3
// baseline (523.989 us; speedup 1.0000x reference)
//
#include <hip/hip_runtime.h>
#include <stdint.h>
#include <math.h>

// Problem constants (B,L,H,D fixed by setup_inputs)
#define Bn 4
#define Ln 2048
#define Hn 8
#define Dn 64
#define BHn (Bn*Hn)
#define NTOP 40   // FACTOR * ceil(log(2048)) = 5*8
#define SK   40
#define NSAMP (Ln*SK)        // 81920

// ---------------- Threefry-2x32 (exact JAX replication) ----------------
__host__ __device__ inline uint32_t rotl32(uint32_t x, int r) {
  return (x << r) | (x >> (32 - r));
}

__host__ __device__ inline void tf2x32(uint32_t k0, uint32_t k1,
                                       uint32_t& x0, uint32_t& x1) {
  const uint32_t ks2 = k0 ^ k1 ^ 0x1BD11BDAu;
  const int RA[4] = {13, 15, 26, 6};
  const int RB[4] = {17, 29, 16, 24};
  x0 += k0; x1 += k1;
  for (int i = 0; i < 4; i++) { x0 += x1; x1 = rotl32(x1, RA[i]); x1 ^= x0; }
  x0 += k1;  x1 += ks2 + 1u;
  for (int i = 0; i < 4; i++) { x0 += x1; x1 = rotl32(x1, RB[i]); x1 ^= x0; }
  x0 += ks2; x1 += k0 + 2u;
  for (int i = 0; i < 4; i++) { x0 += x1; x1 = rotl32(x1, RA[i]); x1 ^= x0; }
  x0 += k0;  x1 += k1 + 3u;
  for (int i = 0; i < 4; i++) { x0 += x1; x1 = rotl32(x1, RB[i]); x1 ^= x0; }
  x0 += k1;  x1 += ks2 + 4u;
  for (int i = 0; i < 4; i++) { x0 += x1; x1 = rotl32(x1, RA[i]); x1 ^= x0; }
  x0 += ks2; x1 += k0 + 5u;
}

// jax_threefry_partitionable=True path (default in modern JAX):
//   random_bits(k2, 32, shape): element j -> ctr (0, j); draw = out0 ^ out1
//   randint pow2 span -> index = draw & 2047
__global__ void gen_samples(int* __restrict__ sample, uint32_t k0, uint32_t k1) {
  int j = blockIdx.x * blockDim.x + threadIdx.x;
  if (j >= NSAMP) return;
  uint32_t x0 = 0u, x1 = (uint32_t)j;
  tf2x32(k0, k1, x0, x1);
  sample[j] = (int)((x0 ^ x1) & (Ln - 1));
}

// ---------------- M = max_s(QK_s) - sum_s(QK_s)/L ----------------
__global__ __launch_bounds__(256) void compute_M(const float* __restrict__ Q,
                                                 const float* __restrict__ K,
                                                 const int* __restrict__ sample,
                                                 float* __restrict__ M) {
  int gid = blockIdx.x * 256 + threadIdx.x;   // B*H*L threads
  int i  = gid & (Ln - 1);
  int bh = gid >> 11;
  const float4* qrow = (const float4*)(Q + ((size_t)bh * Ln + i) * Dn);
  float4 q[16];
#pragma unroll
  for (int t = 0; t < 16; t++) q[t] = qrow[t];
  const float* Kb = K + (size_t)bh * Ln * Dn;
  const int* smp = sample + i * SK;
  float mx = -INFINITY, sm = 0.f;
  for (int s = 0; s < SK; s++) {
    const float4* kr = (const float4*)(Kb + (size_t)smp[s] * Dn);
    float acc = 0.f;
#pragma unroll
    for (int t = 0; t < 16; t++) {
      float4 k4 = kr[t];
      acc += q[t].x * k4.x + q[t].y * k4.y + q[t].z * k4.z + q[t].w * k4.w;
    }
    mx = fmaxf(mx, acc);
    sm += acc;
  }
  M[gid] = mx - sm * (1.0f / (float)Ln);
}

// ---------------- top-40 per (b,h); JAX tie-break: smaller index wins ----------------
__global__ __launch_bounds__(256) void topk_kernel(const float* __restrict__ M,
                                                   int* __restrict__ Mtop) {
  int bh = blockIdx.x;
  __shared__ float vals[Ln];
  __shared__ float rv[256];
  __shared__ int   ri[256];
  const float* m = M + (size_t)bh * Ln;
  for (int t = threadIdx.x; t < Ln; t += 256) vals[t] = m[t];
  __syncthreads();
  int tid = threadIdx.x;
  for (int k = 0; k < NTOP; ++k) {
    float bv = -INFINITY; int bi = Ln;
    for (int t = tid; t < Ln; t += 256) {
      float v = vals[t];
      if (v > bv || (v == bv && t < bi)) { bv = v; bi = t; }
    }
    rv[tid] = bv; ri[tid] = bi;
    __syncthreads();
    if (tid < 64) {
      for (int q = 1; q < 4; q++) {
        float ov = rv[tid + 64 * q]; int oi = ri[tid + 64 * q];
        if (ov > bv || (ov == bv && oi < bi)) { bv = ov; bi = oi; }
      }
      for (int off = 32; off; off >>= 1) {
        float ov = __shfl_xor(bv, off, 64);
        int   oi = __shfl_xor(bi, off, 64);
        if (ov > bv || (ov == bv && oi < bi)) { bv = ov; bi = oi; }
      }
      if (tid == 0) { Mtop[bh * NTOP + k] = bi; vals[bi] = -INFINITY; }
    }
    __syncthreads();
  }
}

// ---------------- context cumsum, phase 1: per-tile (64 l) sums ----------------
__global__ __launch_bounds__(256) void vsum_partial(const float* __restrict__ V,
                                                    float* __restrict__ partial) {
  int tile = blockIdx.x & 31;
  int bh   = blockIdx.x >> 5;
  int d = threadIdx.x & 63;
  int g = threadIdx.x >> 6;
  const float* Vb = V + (size_t)bh * Ln * Dn;
  int l0 = tile * 64 + g * 16;
  float s = 0.f;
  for (int j = 0; j < 16; j++) s += Vb[(size_t)(l0 + j) * Dn + d];
  __shared__ float red[4][64];
  red[g][d] = s;
  __syncthreads();
  if (g == 0)
    partial[((size_t)bh * 32 + tile) * 64 + d] =
        red[0][d] + red[1][d] + red[2][d] + red[3][d];
}

// ---------------- context cumsum, phase 2: prefix + cumsum + transposed write ----------------
__global__ __launch_bounds__(256) void context_write(const float* __restrict__ V,
                                                     const float* __restrict__ partial,
                                                     float* __restrict__ out) {
  int tile = blockIdx.x & 31;
  int bh   = blockIdx.x >> 5;
  int b = bh >> 3, h = bh & 7;
  int d = threadIdx.x & 63;
  int g = threadIdx.x >> 6;
  __shared__ float red[4][64];
  float p = 0.f;
  for (int t = g; t < tile; t += 4)
    p += partial[((size_t)bh * 32 + t) * 64 + d];
  red[g][d] = p;
  __syncthreads();
  float prefix = red[0][d] + red[1][d] + red[2][d] + red[3][d];
  __syncthreads();
  const float* Vb = V + (size_t)bh * Ln * Dn;
  int l0 = tile * 64 + g * 16;
  float vloc[16]; float s = 0.f;
  for (int j = 0; j < 16; j++) {
    vloc[j] = Vb[(size_t)(l0 + j) * Dn + d];
    s += vloc[j];
  }
  red[g][d] = s;
  __syncthreads();
  float running = prefix;
  for (int gg = 0; gg < g; gg++) running += red[gg][d];
  for (int j = 0; j < 16; j++) {
    int l = l0 + j;
    running += vloc[j];
    out[(((size_t)b * Ln + l) * Hn + h) * Dn + d] =
        0.5f * ((float)(l + 1) * vloc[j] + running);
  }
}

// ---------------- sparse attention over the 40 selected rows ----------------
// grid: (B*H) * 8 chunks of UC=5 rows; block 512 (8 waves)
#define UC 5
__global__ __launch_bounds__(512) void sparse_attn(const float* __restrict__ Q,
                                                   const float* __restrict__ K,
                                                   const float* __restrict__ V,
                                                   const int* __restrict__ Mtop,
                                                   float* __restrict__ out) {
  int chunk = blockIdx.x & 7;
  int bh    = blockIdx.x >> 3;
  int b = bh >> 3, h = bh & 7;
  __shared__ float sc[UC][Ln];                       // 40 KB scores->probs
  __shared__ alignas(16) float qs[UC][Dn];
  __shared__ alignas(16) float ks[UC][Dn];
  __shared__ float vs[UC][Dn];
  __shared__ float redp[4][UC][64];                  // 5 KB partial attn@V
  __shared__ int   rows_s[UC];
  __shared__ float inv_s[UC];
  const float* Qb = Q + (size_t)bh * Ln * Dn;
  const float* Kb = K + (size_t)bh * Ln * Dn;
  const float* Vb = V + (size_t)bh * Ln * Dn;
  int tid = threadIdx.x;

  if (tid < UC * 64) {
    int u = tid >> 6, d = tid & 63;
    int row = Mtop[bh * NTOP + chunk * UC + u];
    if (d == 0) rows_s[u] = row;
    qs[u][d] = Qb[(size_t)row * Dn + d];
    ks[u][d] = Kb[(size_t)row * Dn + d];
    vs[u][d] = Vb[(size_t)row * Dn + d];
  }
  __syncthreads();

  // pass 1: scores[u][l] = 0.0625*(Qsel[u].K[l] + Q[l].Ksel[u]), causal mask l>row
  float acc[UC][4];
#pragma unroll
  for (int u = 0; u < UC; u++)
#pragma unroll
    for (int j = 0; j < 4; j++) acc[u][j] = 0.f;
#pragma unroll 4
  for (int t = 0; t < 16; t++) {
    float4 kk[4], qq[4];
#pragma unroll
    for (int j = 0; j < 4; j++) {
      int l = tid + j * 512;
      kk[j] = *(const float4*)(Kb + (size_t)l * Dn + t * 4);
      qq[j] = *(const float4*)(Qb + (size_t)l * Dn + t * 4);
    }
#pragma unroll
    for (int u = 0; u < UC; u++) {
      float4 q4 = *(const float4*)(&qs[u][t * 4]);
      float4 k4 = *(const float4*)(&ks[u][t * 4]);
#pragma unroll
      for (int j = 0; j < 4; j++) {
        acc[u][j] += q4.x * kk[j].x + q4.y * kk[j].y + q4.z * kk[j].z + q4.w * kk[j].w
                   + k4.x * qq[j].x + k4.y * qq[j].y + k4.z * qq[j].z + k4.w * qq[j].w;
      }
    }
  }
#pragma unroll
  for (int u = 0; u < UC; u++) {
    int row = rows_s[u];
#pragma unroll
    for (int j = 0; j < 4; j++) {
      int l = tid + j * 512;
      sc[u][l] = (l > row) ? -1e9f : acc[u][j] * 0.0625f;
    }
  }
  __syncthreads();

  // pass 2: softmax per u; wave w handles u=w (waves 0..4)
  int w = tid >> 6, lane = tid & 63;
  if (w < UC) {
    float mx = -INFINITY;
    for (int kq = 0; kq < 32; kq++) mx = fmaxf(mx, sc[w][lane + 64 * kq]);
    for (int off = 32; off; off >>= 1) mx = fmaxf(mx, __shfl_xor(mx, off, 64));
    float sum = 0.f;
    for (int kq = 0; kq < 32; kq++) {
      float e = __expf(sc[w][lane + 64 * kq] - mx);
      sc[w][lane + 64 * kq] = e;
      sum += e;
    }
    for (int off = 32; off; off >>= 1) sum += __shfl_xor(sum, off, 64);
    if (lane == 0) inv_s[w] = 1.0f / sum;
  }
  __syncthreads();

  // pass 3: attn @ V ; l split in 4 quarters, u split by wave>>2
  int g = w & 3, uh = w >> 2;
  int l0 = g * 512;
  if (uh == 0) {
    float a0 = 0, a1 = 0, a2 = 0;
    for (int l = l0; l < l0 + 512; ++l) {
      float v = Vb[(size_t)l * Dn + lane];
      a0 += sc[0][l] * v; a1 += sc[2][l] * v; a2 += sc[4][l] * v;
    }
    redp[g][0][lane] = a0; redp[g][2][lane] = a1; redp[g][4][lane] = a2;
  } else {
    float a0 = 0, a1 = 0;
    for (int l = l0; l < l0 + 512; ++l) {
      float v = Vb[(size_t)l * Dn + lane];
      a0 += sc[1][l] * v; a1 += sc[3][l] * v;
    }
    redp[g][1][lane] = a0; redp[g][3][lane] = a1;
  }
  __syncthreads();

  if (w < UC) {
    float r = redp[0][w][lane] + redp[1][w][lane] + redp[2][w][lane] + redp[3][w][lane];
    float outv = 0.5f * (vs[w][lane] + r * inv_s[w]);
    int row = rows_s[w];
    out[(((size_t)b * Ln + row) * Hn + h) * Dn + lane] = outv;
  }
}

extern "C" void kernel_launch(void* const* d_in, const int* in_sizes, int n_in,
                              void* d_out, int out_size, void* d_ws, size_t ws_size,
                              hipStream_t stream) {
  const float* Q = (const float*)d_in[0];  // (B,L,H,D) flat == (B,H,L,D) reshape
  const float* K = (const float*)d_in[1];
  const float* V = (const float*)d_in[2];
  float* out = (float*)d_out;
  char* ws = (char*)d_ws;

  int*   sample  = (int*)ws;                                       // 81920 ints
  float* M       = (float*)(ws + NSAMP * 4);                       // 65536 f32
  int*   Mtop    = (int*)(ws + NSAMP * 4 + BHn * Ln * 4);          // 1280 ints
  float* partial = (float*)(ws + NSAMP * 4 + BHn * Ln * 4 + BHn * NTOP * 4); // 65536 f32

  // Partitionable threefry split of key(42) = (0,42):
  // split counters from iota_2x32_shape((2,)) -> elem i has ctr (0, i);
  // k2 = (out0, out1) of block with ctr (0, 1).
  uint32_t s0 = 0u, s1 = 1u;
  tf2x32(0u, 42u, s0, s1);   // s0,s1 = k2

  gen_samples<<<NSAMP / 256, 256, 0, stream>>>(sample, s0, s1);
  compute_M<<<(BHn * Ln) / 256, 256, 0, stream>>>(Q, K, sample, M);
  topk_kernel<<<BHn, 256, 0, stream>>>(M, Mtop);
  vsum_partial<<<BHn * 32, 256, 0, stream>>>(V, partial);
  context_write<<<BHn * 32, 256, 0, stream>>>(V, partial, out);
  sparse_attn<<<BHn * 8, 512, 0, stream>>>(Q, K, V, Mtop, out);
}

// Round 4
// 304.637 us; speedup vs baseline: 1.7200x; 1.7200x over previous
//
#include <hip/hip_runtime.h>
#include <stdint.h>
#include <math.h>

// Problem constants (B,L,H,D fixed by setup_inputs)
#define Bn 4
#define Ln 2048
#define Hn 8
#define Dn 64
#define BHn (Bn*Hn)
#define NTOP 40   // FACTOR * ceil(log(2048)) = 5*8
#define SK   40
#define NSAMP (Ln*SK)        // 81920

// ---------------- Threefry-2x32 (exact JAX replication) ----------------
__host__ __device__ inline uint32_t rotl32(uint32_t x, int r) {
  return (x << r) | (x >> (32 - r));
}

__host__ __device__ inline void tf2x32(uint32_t k0, uint32_t k1,
                                       uint32_t& x0, uint32_t& x1) {
  const uint32_t ks2 = k0 ^ k1 ^ 0x1BD11BDAu;
  const int RA[4] = {13, 15, 26, 6};
  const int RB[4] = {17, 29, 16, 24};
  x0 += k0; x1 += k1;
  for (int i = 0; i < 4; i++) { x0 += x1; x1 = rotl32(x1, RA[i]); x1 ^= x0; }
  x0 += k1;  x1 += ks2 + 1u;
  for (int i = 0; i < 4; i++) { x0 += x1; x1 = rotl32(x1, RB[i]); x1 ^= x0; }
  x0 += ks2; x1 += k0 + 2u;
  for (int i = 0; i < 4; i++) { x0 += x1; x1 = rotl32(x1, RA[i]); x1 ^= x0; }
  x0 += k0;  x1 += k1 + 3u;
  for (int i = 0; i < 4; i++) { x0 += x1; x1 = rotl32(x1, RB[i]); x1 ^= x0; }
  x0 += k1;  x1 += ks2 + 4u;
  for (int i = 0; i < 4; i++) { x0 += x1; x1 = rotl32(x1, RA[i]); x1 ^= x0; }
  x0 += ks2; x1 += k0 + 5u;
}

// jax_threefry_partitionable=True: elem j -> ctr (0, j); draw = out0 ^ out1
__global__ void gen_samples(int* __restrict__ sample, uint32_t k0, uint32_t k1) {
  int j = blockIdx.x * blockDim.x + threadIdx.x;
  if (j >= NSAMP) return;
  uint32_t x0 = 0u, x1 = (uint32_t)j;
  tf2x32(k0, k1, x0, x1);
  sample[j] = (int)((x0 ^ x1) & (Ln - 1));
}

// ---------------- M = max_s(QK_s) - sum_s(QK_s)/L ----------------
// XCD swizzle: blk&7 = xcd; 4 distinct bh per xcd (2 MB K working set < 4 MB L2).
// 4 parallel acc chains -> 4x memory-level parallelism.
__global__ __launch_bounds__(256) void compute_M(const float* __restrict__ Q,
                                                 const float* __restrict__ K,
                                                 const int* __restrict__ sample,
                                                 float* __restrict__ M) {
  int xcd = blockIdx.x & 7;
  int s   = blockIdx.x >> 3;            // 0..31
  int bh  = (s >> 3) * 8 + xcd;         // {xcd, xcd+8, xcd+16, xcd+24}
  int i   = (s & 7) * 256 + threadIdx.x;
  const float4* qrow = (const float4*)(Q + ((size_t)bh * Ln + i) * Dn);
  float4 q[16];
#pragma unroll
  for (int t = 0; t < 16; t++) q[t] = qrow[t];
  const float* Kb = K + (size_t)bh * Ln * Dn;
  const int4* smp4 = (const int4*)(sample + i * SK);
  float mx = -INFINITY, sm = 0.f;
  for (int g = 0; g < 10; g++) {
    int4 id = smp4[g];
    const float4* r0 = (const float4*)(Kb + (size_t)id.x * Dn);
    const float4* r1 = (const float4*)(Kb + (size_t)id.y * Dn);
    const float4* r2 = (const float4*)(Kb + (size_t)id.z * Dn);
    const float4* r3 = (const float4*)(Kb + (size_t)id.w * Dn);
    float a0 = 0.f, a1 = 0.f, a2 = 0.f, a3 = 0.f;
#pragma unroll
    for (int t = 0; t < 16; t++) {
      float4 k0 = r0[t], k1 = r1[t], k2 = r2[t], k3 = r3[t];
      a0 += q[t].x * k0.x + q[t].y * k0.y + q[t].z * k0.z + q[t].w * k0.w;
      a1 += q[t].x * k1.x + q[t].y * k1.y + q[t].z * k1.z + q[t].w * k1.w;
      a2 += q[t].x * k2.x + q[t].y * k2.y + q[t].z * k2.z + q[t].w * k2.w;
      a3 += q[t].x * k3.x + q[t].y * k3.y + q[t].z * k3.z + q[t].w * k3.w;
    }
    mx = fmaxf(mx, fmaxf(fmaxf(a0, a1), fmaxf(a2, a3)));
    sm += a0 + a1 + a2 + a3;
  }
  M[(size_t)bh * Ln + i] = mx - sm * (1.0f / (float)Ln);
}

// ---------------- top-40: stage 1, per-256-segment top-40 ----------------
__global__ __launch_bounds__(256) void topk_stage1(const float* __restrict__ M,
                                                   float* __restrict__ cval,
                                                   int* __restrict__ cidx) {
  int bh = blockIdx.x >> 3, seg = blockIdx.x & 7;
  int tid = threadIdx.x, lane = tid & 63, w = tid >> 6;
  __shared__ float rv[4];
  __shared__ int   ri[4];
  __shared__ int   sel;
  float cur = M[(size_t)bh * Ln + seg * 256 + tid];
  for (int k = 0; k < NTOP; ++k) {
    float bv = cur; int bi = tid;
    for (int off = 32; off; off >>= 1) {
      float ov = __shfl_xor(bv, off, 64);
      int   oi = __shfl_xor(bi, off, 64);
      if (ov > bv || (ov == bv && oi < bi)) { bv = ov; bi = oi; }
    }
    if (lane == 0) { rv[w] = bv; ri[w] = bi; }
    __syncthreads();
    if (tid == 0) {
      float xv = rv[0]; int xi = ri[0];
      for (int q = 1; q < 4; q++)
        if (rv[q] > xv || (rv[q] == xv && ri[q] < xi)) { xv = rv[q]; xi = ri[q]; }
      sel = xi;
      cval[blockIdx.x * NTOP + k] = xv;
      cidx[blockIdx.x * NTOP + k] = seg * 256 + xi;
    }
    __syncthreads();
    if (tid == sel) cur = -INFINITY;
  }
}

// ---------------- top-40: stage 2, merge 8*40=320 candidates ----------------
__global__ __launch_bounds__(320) void topk_stage2(const float* __restrict__ cval,
                                                   const int* __restrict__ cidx,
                                                   int* __restrict__ Mtop) {
  int bh = blockIdx.x;
  int tid = threadIdx.x, lane = tid & 63, w = tid >> 6;
  __shared__ float rv[5];
  __shared__ int   rg[5], rt[5];
  __shared__ int   sel;
  float cur = cval[bh * 320 + tid];
  int   gidx = cidx[bh * 320 + tid];
  for (int k = 0; k < NTOP; ++k) {
    float bv = cur; int bg = gidx; int bt = tid;
    for (int off = 32; off; off >>= 1) {
      float ov = __shfl_xor(bv, off, 64);
      int   og = __shfl_xor(bg, off, 64);
      int   ot = __shfl_xor(bt, off, 64);
      if (ov > bv || (ov == bv && og < bg)) { bv = ov; bg = og; bt = ot; }
    }
    if (lane == 0) { rv[w] = bv; rg[w] = bg; rt[w] = bt; }
    __syncthreads();
    if (tid == 0) {
      float xv = rv[0]; int xg = rg[0]; int xt = rt[0];
      for (int q = 1; q < 5; q++)
        if (rv[q] > xv || (rv[q] == xv && rg[q] < xg)) { xv = rv[q]; xg = rg[q]; xt = rt[q]; }
      sel = xt;
      Mtop[bh * NTOP + k] = xg;
    }
    __syncthreads();
    if (tid == sel) cur = -INFINITY;
  }
}

// ---------------- context cumsum, phase 1: per-tile (64 l) sums ----------------
__global__ __launch_bounds__(256) void vsum_partial(const float* __restrict__ V,
                                                    float* __restrict__ partial) {
  int tile = blockIdx.x & 31;
  int bh   = blockIdx.x >> 5;
  int d = threadIdx.x & 63;
  int g = threadIdx.x >> 6;
  const float* Vb = V + (size_t)bh * Ln * Dn;
  int l0 = tile * 64 + g * 16;
  float s = 0.f;
  for (int j = 0; j < 16; j++) s += Vb[(size_t)(l0 + j) * Dn + d];
  __shared__ float red[4][64];
  red[g][d] = s;
  __syncthreads();
  if (g == 0)
    partial[((size_t)bh * 32 + tile) * 64 + d] =
        red[0][d] + red[1][d] + red[2][d] + red[3][d];
}

// ---------------- context cumsum, phase 2: prefix + cumsum + transposed write ----------------
__global__ __launch_bounds__(256) void context_write(const float* __restrict__ V,
                                                     const float* __restrict__ partial,
                                                     float* __restrict__ out) {
  int tile = blockIdx.x & 31;
  int bh   = blockIdx.x >> 5;
  int b = bh >> 3, h = bh & 7;
  int d = threadIdx.x & 63;
  int g = threadIdx.x >> 6;
  __shared__ float red[4][64];
  float p = 0.f;
  for (int t = g; t < tile; t += 4)
    p += partial[((size_t)bh * 32 + t) * 64 + d];
  red[g][d] = p;
  __syncthreads();
  float prefix = red[0][d] + red[1][d] + red[2][d] + red[3][d];
  __syncthreads();
  const float* Vb = V + (size_t)bh * Ln * Dn;
  int l0 = tile * 64 + g * 16;
  float vloc[16]; float s = 0.f;
  for (int j = 0; j < 16; j++) {
    vloc[j] = Vb[(size_t)(l0 + j) * Dn + d];
    s += vloc[j];
  }
  red[g][d] = s;
  __syncthreads();
  float running = prefix;
  for (int gg = 0; gg < g; gg++) running += red[gg][d];
  for (int j = 0; j < 16; j++) {
    int l = l0 + j;
    running += vloc[j];
    out[(((size_t)b * Ln + l) * Hn + h) * Dn + d] =
        0.5f * ((float)(l + 1) * vloc[j] + running);
  }
}

// ---------------- sparse attention over the 40 selected rows ----------------
// XCD swizzle: all 8 chunks of one bh share an XCD (L2 reuse of Q/K/V).
// Pass 1: 32 float4 loads in flight per thread. Pass 3: wave w owns a unique
// 256-l slice for all 5 u (V read once, coalesced; sc via broadcast b128).
#define UC 5
__global__ __launch_bounds__(512, 2) void sparse_attn(const float* __restrict__ Q,
                                                      const float* __restrict__ K,
                                                      const float* __restrict__ V,
                                                      const int* __restrict__ Mtop,
                                                      float* __restrict__ out) {
  int xcd  = blockIdx.x & 7;
  int rest = blockIdx.x >> 3;     // 0..31
  int chunk = rest & 7;
  int bh    = (rest >> 3) * 8 + xcd;
  int b = bh >> 3, h = bh & 7;
  __shared__ alignas(16) float sc[UC][Ln];           // 40 KB scores->probs
  __shared__ alignas(16) float qs[UC][Dn];
  __shared__ alignas(16) float ks[UC][Dn];
  __shared__ float vs[UC][Dn];
  __shared__ float redp[8][UC][64];                  // 10 KB partial attn@V
  __shared__ int   rows_s[UC];
  __shared__ float inv_s[UC];
  const float* Qb = Q + (size_t)bh * Ln * Dn;
  const float* Kb = K + (size_t)bh * Ln * Dn;
  const float* Vb = V + (size_t)bh * Ln * Dn;
  int tid = threadIdx.x;

  if (tid < UC * 64) {
    int u = tid >> 6, d = tid & 63;
    int row = Mtop[bh * NTOP + chunk * UC + u];
    if (d == 0) rows_s[u] = row;
    qs[u][d] = Qb[(size_t)row * Dn + d];
    ks[u][d] = Kb[(size_t)row * Dn + d];
    vs[u][d] = Vb[(size_t)row * Dn + d];
  }
  __syncthreads();

  // pass 1: scores[u][l] = 0.0625*(Qsel[u].K[l] + Q[l].Ksel[u]), causal mask l>row
  float acc[UC][4];
#pragma unroll
  for (int u = 0; u < UC; u++)
#pragma unroll
    for (int j = 0; j < 4; j++) acc[u][j] = 0.f;

  for (int tt = 0; tt < 4; tt++) {
    float4 kk[4][4], qq[4][4];    // [j][ts] — 32 loads issued before use
#pragma unroll
    for (int j = 0; j < 4; j++) {
      int l = tid + j * 512;
      const float4* kp = (const float4*)(Kb + (size_t)l * Dn) + tt * 4;
      const float4* qp = (const float4*)(Qb + (size_t)l * Dn) + tt * 4;
#pragma unroll
      for (int ts = 0; ts < 4; ts++) { kk[j][ts] = kp[ts]; qq[j][ts] = qp[ts]; }
    }
#pragma unroll
    for (int ts = 0; ts < 4; ts++) {
      int t = tt * 4 + ts;
#pragma unroll
      for (int u = 0; u < UC; u++) {
        float4 q4 = *(const float4*)(&qs[u][t * 4]);
        float4 k4 = *(const float4*)(&ks[u][t * 4]);
#pragma unroll
        for (int j = 0; j < 4; j++) {
          acc[u][j] += q4.x * kk[j][ts].x + q4.y * kk[j][ts].y
                     + q4.z * kk[j][ts].z + q4.w * kk[j][ts].w
                     + k4.x * qq[j][ts].x + k4.y * qq[j][ts].y
                     + k4.z * qq[j][ts].z + k4.w * qq[j][ts].w;
        }
      }
    }
  }
#pragma unroll
  for (int u = 0; u < UC; u++) {
    int row = rows_s[u];
#pragma unroll
    for (int j = 0; j < 4; j++) {
      int l = tid + j * 512;
      sc[u][l] = (l > row) ? -1e9f : acc[u][j] * 0.0625f;
    }
  }
  __syncthreads();

  // pass 2: softmax per u; wave w handles u=w (waves 0..4)
  int w = tid >> 6, lane = tid & 63;
  if (w < UC) {
    float mx = -INFINITY;
    for (int kq = 0; kq < 32; kq++) mx = fmaxf(mx, sc[w][lane + 64 * kq]);
    for (int off = 32; off; off >>= 1) mx = fmaxf(mx, __shfl_xor(mx, off, 64));
    float sum = 0.f;
    for (int kq = 0; kq < 32; kq++) {
      float e = __expf(sc[w][lane + 64 * kq] - mx);
      sc[w][lane + 64 * kq] = e;
      sum += e;
    }
    for (int off = 32; off; off >>= 1) sum += __shfl_xor(sum, off, 64);
    if (lane == 0) inv_s[w] = 1.0f / sum;
  }
  __syncthreads();

  // pass 3: attn @ V ; wave w owns l in [w*256, w*256+256) for ALL 5 u
  {
    int l0w = w * 256;
    float a[UC] = {0.f, 0.f, 0.f, 0.f, 0.f};
    for (int lq = 0; lq < 256; lq += 8) {
      int lb = l0w + lq;
      float v[8];
#pragma unroll
      for (int r = 0; r < 8; r++) v[r] = Vb[(size_t)(lb + r) * Dn + lane];
#pragma unroll
      for (int u = 0; u < UC; u++) {
        float4 sa = *(const float4*)(&sc[u][lb]);
        float4 sb = *(const float4*)(&sc[u][lb + 4]);
        a[u] += sa.x * v[0] + sa.y * v[1] + sa.z * v[2] + sa.w * v[3]
              + sb.x * v[4] + sb.y * v[5] + sb.z * v[6] + sb.w * v[7];
      }
    }
#pragma unroll
    for (int u = 0; u < UC; u++) redp[w][u][lane] = a[u];
  }
  __syncthreads();

  if (w < UC) {
    float r = 0.f;
#pragma unroll
    for (int g = 0; g < 8; g++) r += redp[g][w][lane];
    float outv = 0.5f * (vs[w][lane] + r * inv_s[w]);
    int row = rows_s[w];
    out[(((size_t)b * Ln + row) * Hn + h) * Dn + lane] = outv;
  }
}

extern "C" void kernel_launch(void* const* d_in, const int* in_sizes, int n_in,
                              void* d_out, int out_size, void* d_ws, size_t ws_size,
                              hipStream_t stream) {
  const float* Q = (const float*)d_in[0];  // (B,L,H,D) flat == (B,H,L,D) reshape
  const float* K = (const float*)d_in[1];
  const float* V = (const float*)d_in[2];
  float* out = (float*)d_out;
  char* ws = (char*)d_ws;

  int*   sample  = (int*)ws;                                       // 320 KB
  float* M       = (float*)(ws + NSAMP * 4);                       // 256 KB
  int*   Mtop    = (int*)(ws + NSAMP * 4 + BHn * Ln * 4);          // 5 KB
  float* partial = (float*)(ws + NSAMP * 4 + BHn * Ln * 4 + BHn * NTOP * 4); // 256 KB
  // cval/cidx alias the sample region: sample is dead after compute_M,
  // and kernels on one stream serialize, so this is race-free.
  float* cval = (float*)ws;                       // 40 KB (BHn*8*NTOP)
  int*   cidx = (int*)(ws + BHn * 8 * NTOP * 4);  // 40 KB

  // Partitionable threefry split of key(42) = (0,42): k2 = tf(key, ctr=(0,1)).
  uint32_t s0 = 0u, s1 = 1u;
  tf2x32(0u, 42u, s0, s1);

  gen_samples<<<NSAMP / 256, 256, 0, stream>>>(sample, s0, s1);
  compute_M<<<(BHn * Ln) / (256 * 8) * 8, 256, 0, stream>>>(Q, K, sample, M);
  topk_stage1<<<BHn * 8, 256, 0, stream>>>(M, cval, cidx);
  topk_stage2<<<BHn, 320, 0, stream>>>(cval, cidx, Mtop);
  vsum_partial<<<BHn * 32, 256, 0, stream>>>(V, partial);
  context_write<<<BHn * 32, 256, 0, stream>>>(V, partial, out);
  sparse_attn<<<BHn * 8, 512, 0, stream>>>(Q, K, V, Mtop, out);
}